// Round 6
// baseline (217.264 us; speedup 1.0000x reference)
//
#include <hip/hip_runtime.h>
#include <stdint.h>

#define NCLS 14
#define BATCH 2
#define NUM_BINS (BATCH * NCLS)

// d_ws layout: float sums[NUM_BINS] | int counts[NUM_BINS]

__global__ void zero_bins_kernel(float* __restrict__ sums, int* __restrict__ counts) {
    int i = threadIdx.x;
    if (i < NUM_BINS) { sums[i] = 0.0f; counts[i] = 0; }
}

__global__ __launch_bounds__(256) void kl_kernel(
        const float* __restrict__ S, const float* __restrict__ T,
        const int* __restrict__ gt,
        float* __restrict__ gsums, int* __restrict__ gcnts,
        int N /* voxels per batch image */) {
    __shared__ float lsum[NUM_BINS];
    __shared__ int lcnt[NUM_BINS];
    if (threadIdx.x < NUM_BINS) { lsum[threadIdx.x] = 0.0f; lcnt[threadIdx.x] = 0; }
    __syncthreads();

    // b computed from blockIdx ONLY -> block-uniform -> SGPR base pointers.
    // Legal because N % blockDim == 0: a block never straddles the batch edge.
    const int b = (blockIdx.x * blockDim.x >= (unsigned)N) ? 1 : 0;
    const int v0 = blockIdx.x * blockDim.x + threadIdx.x;  // one voxel per thread
    const int n = v0 - b * N;

    const float* Sb = S + (size_t)b * NCLS * N;   // uniform (SGPR pair)
    const float* Tb = T + (size_t)b * NCLS * N;   // uniform (SGPR pair)
    const uint32_t voff = (uint32_t)n * 4u;       // per-lane byte offset (VGPR)

    float sv[NCLS], tv[NCLS];

    // ---- Force 28 independent loads in flight: saddr-form inline-asm loads.
    asm volatile(
        "global_load_dword %[d0], %[vo], %[p0]\n\t"
        "global_load_dword %[d1], %[vo], %[p1]\n\t"
        "global_load_dword %[d2], %[vo], %[p2]\n\t"
        "global_load_dword %[d3], %[vo], %[p3]\n\t"
        "global_load_dword %[d4], %[vo], %[p4]\n\t"
        "global_load_dword %[d5], %[vo], %[p5]\n\t"
        "global_load_dword %[d6], %[vo], %[p6]\n\t"
        : [d0]"=v"(sv[0]), [d1]"=v"(sv[1]), [d2]"=v"(sv[2]), [d3]"=v"(sv[3]),
          [d4]"=v"(sv[4]), [d5]"=v"(sv[5]), [d6]"=v"(sv[6])
        : [vo]"v"(voff),
          [p0]"s"(Sb + 0*(size_t)N), [p1]"s"(Sb + 1*(size_t)N),
          [p2]"s"(Sb + 2*(size_t)N), [p3]"s"(Sb + 3*(size_t)N),
          [p4]"s"(Sb + 4*(size_t)N), [p5]"s"(Sb + 5*(size_t)N),
          [p6]"s"(Sb + 6*(size_t)N));
    asm volatile(
        "global_load_dword %[d0], %[vo], %[p0]\n\t"
        "global_load_dword %[d1], %[vo], %[p1]\n\t"
        "global_load_dword %[d2], %[vo], %[p2]\n\t"
        "global_load_dword %[d3], %[vo], %[p3]\n\t"
        "global_load_dword %[d4], %[vo], %[p4]\n\t"
        "global_load_dword %[d5], %[vo], %[p5]\n\t"
        "global_load_dword %[d6], %[vo], %[p6]\n\t"
        : [d0]"=v"(sv[7]), [d1]"=v"(sv[8]), [d2]"=v"(sv[9]), [d3]"=v"(sv[10]),
          [d4]"=v"(sv[11]), [d5]"=v"(sv[12]), [d6]"=v"(sv[13])
        : [vo]"v"(voff),
          [p0]"s"(Sb + 7*(size_t)N), [p1]"s"(Sb + 8*(size_t)N),
          [p2]"s"(Sb + 9*(size_t)N), [p3]"s"(Sb + 10*(size_t)N),
          [p4]"s"(Sb + 11*(size_t)N), [p5]"s"(Sb + 12*(size_t)N),
          [p6]"s"(Sb + 13*(size_t)N));
    asm volatile(
        "global_load_dword %[d0], %[vo], %[p0]\n\t"
        "global_load_dword %[d1], %[vo], %[p1]\n\t"
        "global_load_dword %[d2], %[vo], %[p2]\n\t"
        "global_load_dword %[d3], %[vo], %[p3]\n\t"
        "global_load_dword %[d4], %[vo], %[p4]\n\t"
        "global_load_dword %[d5], %[vo], %[p5]\n\t"
        "global_load_dword %[d6], %[vo], %[p6]\n\t"
        : [d0]"=v"(tv[0]), [d1]"=v"(tv[1]), [d2]"=v"(tv[2]), [d3]"=v"(tv[3]),
          [d4]"=v"(tv[4]), [d5]"=v"(tv[5]), [d6]"=v"(tv[6])
        : [vo]"v"(voff),
          [p0]"s"(Tb + 0*(size_t)N), [p1]"s"(Tb + 1*(size_t)N),
          [p2]"s"(Tb + 2*(size_t)N), [p3]"s"(Tb + 3*(size_t)N),
          [p4]"s"(Tb + 4*(size_t)N), [p5]"s"(Tb + 5*(size_t)N),
          [p6]"s"(Tb + 6*(size_t)N));
    asm volatile(
        "global_load_dword %[d0], %[vo], %[p0]\n\t"
        "global_load_dword %[d1], %[vo], %[p1]\n\t"
        "global_load_dword %[d2], %[vo], %[p2]\n\t"
        "global_load_dword %[d3], %[vo], %[p3]\n\t"
        "global_load_dword %[d4], %[vo], %[p4]\n\t"
        "global_load_dword %[d5], %[vo], %[p5]\n\t"
        "global_load_dword %[d6], %[vo], %[p6]\n\t"
        : [d0]"=v"(tv[7]), [d1]"=v"(tv[8]), [d2]"=v"(tv[9]), [d3]"=v"(tv[10]),
          [d4]"=v"(tv[11]), [d5]"=v"(tv[12]), [d6]"=v"(tv[13])
        : [vo]"v"(voff),
          [p0]"s"(Tb + 7*(size_t)N), [p1]"s"(Tb + 8*(size_t)N),
          [p2]"s"(Tb + 9*(size_t)N), [p3]"s"(Tb + 10*(size_t)N),
          [p4]"s"(Tb + 11*(size_t)N), [p5]"s"(Tb + 12*(size_t)N),
          [p6]"s"(Tb + 13*(size_t)N));

    const int g = gt[v0];

    // Single drain; all 28 values tied through as inout so no consumer hoists.
    asm volatile("s_waitcnt vmcnt(0)"
        : "+v"(sv[0]), "+v"(sv[1]), "+v"(sv[2]), "+v"(sv[3]), "+v"(sv[4]),
          "+v"(sv[5]), "+v"(sv[6]), "+v"(sv[7]), "+v"(sv[8]), "+v"(sv[9]),
          "+v"(sv[10]), "+v"(sv[11]), "+v"(sv[12]), "+v"(sv[13]),
          "+v"(tv[0]), "+v"(tv[1]), "+v"(tv[2]), "+v"(tv[3]), "+v"(tv[4]),
          "+v"(tv[5]), "+v"(tv[6]), "+v"(tv[7]), "+v"(tv[8]), "+v"(tv[9]),
          "+v"(tv[10]), "+v"(tv[11]), "+v"(tv[12]), "+v"(tv[13]));
    __builtin_amdgcn_sched_barrier(0);

    float Zs = 0.f, Zt = 0.f, At = 0.f, As = 0.f;
#pragma unroll
    for (int c = 0; c < NCLS; ++c) {
        float et = __expf(tv[c]);
        Zt += et;
        At = fmaf(et, tv[c], At);
        As = fmaf(et, sv[c], As);
        Zs += __expf(sv[c]);
    }
    // kl = sum_c q(logq - logp) = (At - As)/Zt - log(Zt) + log(Zs)
    float kl = (At - As) / Zt - __logf(Zt) + __logf(Zs);

    int c = min(max(g, 0), NCLS - 1);
    atomicAdd(&lsum[b * NCLS + c], kl);
    atomicAdd(&lcnt[b * NCLS + c], 1);

    __syncthreads();
    if (threadIdx.x < NUM_BINS) {
        atomicAdd(&gsums[threadIdx.x], lsum[threadIdx.x]);
        atomicAdd(&gcnts[threadIdx.x], lcnt[threadIdx.x]);
    }
}

__global__ void finalize_kernel(const float* __restrict__ sums,
                                const int* __restrict__ counts,
                                float* __restrict__ out) {
    if (threadIdx.x == 0) {
        float loss = 0.0f;
        for (int b = 0; b < BATCH; ++b) {
            for (int cls = 1; cls < NCLS; ++cls) {   // class 0 (background) excluded
                int idx = b * NCLS + cls;
                int cnt = counts[idx];
                if (cnt > 0) loss += sums[idx] / ((float)NCLS * (float)cnt);
            }
        }
        out[0] = loss;  // TAU^2 = 1, LOSS_WEIGHT = 1
    }
}

extern "C" void kernel_launch(void* const* d_in, const int* in_sizes, int n_in,
                              void* d_out, int out_size, void* d_ws, size_t ws_size,
                              hipStream_t stream) {
    const float* S = (const float*)d_in[0];
    const float* T = (const float*)d_in[1];
    const int* gt = (const int*)d_in[2];
    float* out = (float*)d_out;

    float* sums = (float*)d_ws;
    int* cnts = (int*)((char*)d_ws + NUM_BINS * sizeof(float));

    const int totalVox = in_sizes[2];       // B * 96^3 = 1,769,472 = 6912 * 256
    const int N = totalVox / BATCH;         // 884,736 (divisible by 256)

    const int block = 256;
    const int grid = totalVox / block;      // 6912, exact

    zero_bins_kernel<<<1, 64, 0, stream>>>(sums, cnts);
    kl_kernel<<<grid, block, 0, stream>>>(S, T, gt, sums, cnts, N);
    finalize_kernel<<<1, 64, 0, stream>>>(sums, cnts, out);
}

// Round 7
// 121.048 us; speedup vs baseline: 1.7949x; 1.7949x over previous
//
#include <hip/hip_runtime.h>
#include <stdint.h>

#define NCLS 14
#define BATCH 2
#define NUM_BINS (BATCH * NCLS)

// Round-7 resubmit of the forced-MLP design (round 6 measured a stale binary:
// VGPR_Count=20 is impossible with 28 pinned asm outputs). Kernels renamed,
// loads widened to dwordx2 (2 voxels/thread).
// d_ws layout: float sums[NUM_BINS] | int counts[NUM_BINS]

__global__ void kd_zero_bins(float* __restrict__ sums, int* __restrict__ counts) {
    int i = threadIdx.x;
    if (i < NUM_BINS) { sums[i] = 0.0f; counts[i] = 0; }
}

__global__ __launch_bounds__(256) void kd_kl_mlp2(
        const float* __restrict__ S, const float* __restrict__ T,
        const int* __restrict__ gt,
        float* __restrict__ gsums, int* __restrict__ gcnts,
        int N /* voxels per batch image */) {
    __shared__ float lsum[NUM_BINS];
    __shared__ int lcnt[NUM_BINS];
    if (threadIdx.x < NUM_BINS) { lsum[threadIdx.x] = 0.0f; lcnt[threadIdx.x] = 0; }
    __syncthreads();

    // Pair index; each thread owns voxels {2p, 2p+1}. N % 512 == 0 so a block
    // (512 voxels) never straddles the batch edge -> b is block-uniform ->
    // channel base pointers live in SGPR pairs (saddr-form loads legal).
    const int p = blockIdx.x * blockDim.x + threadIdx.x;
    const int b = (blockIdx.x * (blockDim.x * 2) >= (unsigned)N) ? 1 : 0;
    const int n = p * 2 - b * N;                  // within-batch voxel index

    const float* Sb = S + (size_t)b * NCLS * N;   // uniform (SGPR pair)
    const float* Tb = T + (size_t)b * NCLS * N;   // uniform (SGPR pair)
    const uint32_t voff = (uint32_t)n * 4u;       // per-lane byte offset (VGPR)

    float2 sv[NCLS], tv[NCLS];

    // ---- Force 28 independent dwordx2 loads in flight (14 KB/wave). ----
    asm volatile(
        "global_load_dwordx2 %[d0], %[vo], %[p0]\n\t"
        "global_load_dwordx2 %[d1], %[vo], %[p1]\n\t"
        "global_load_dwordx2 %[d2], %[vo], %[p2]\n\t"
        "global_load_dwordx2 %[d3], %[vo], %[p3]\n\t"
        "global_load_dwordx2 %[d4], %[vo], %[p4]\n\t"
        "global_load_dwordx2 %[d5], %[vo], %[p5]\n\t"
        "global_load_dwordx2 %[d6], %[vo], %[p6]\n\t"
        : [d0]"=v"(sv[0]), [d1]"=v"(sv[1]), [d2]"=v"(sv[2]), [d3]"=v"(sv[3]),
          [d4]"=v"(sv[4]), [d5]"=v"(sv[5]), [d6]"=v"(sv[6])
        : [vo]"v"(voff),
          [p0]"s"(Sb + 0*(size_t)N), [p1]"s"(Sb + 1*(size_t)N),
          [p2]"s"(Sb + 2*(size_t)N), [p3]"s"(Sb + 3*(size_t)N),
          [p4]"s"(Sb + 4*(size_t)N), [p5]"s"(Sb + 5*(size_t)N),
          [p6]"s"(Sb + 6*(size_t)N));
    asm volatile(
        "global_load_dwordx2 %[d0], %[vo], %[p0]\n\t"
        "global_load_dwordx2 %[d1], %[vo], %[p1]\n\t"
        "global_load_dwordx2 %[d2], %[vo], %[p2]\n\t"
        "global_load_dwordx2 %[d3], %[vo], %[p3]\n\t"
        "global_load_dwordx2 %[d4], %[vo], %[p4]\n\t"
        "global_load_dwordx2 %[d5], %[vo], %[p5]\n\t"
        "global_load_dwordx2 %[d6], %[vo], %[p6]\n\t"
        : [d0]"=v"(sv[7]), [d1]"=v"(sv[8]), [d2]"=v"(sv[9]), [d3]"=v"(sv[10]),
          [d4]"=v"(sv[11]), [d5]"=v"(sv[12]), [d6]"=v"(sv[13])
        : [vo]"v"(voff),
          [p0]"s"(Sb + 7*(size_t)N), [p1]"s"(Sb + 8*(size_t)N),
          [p2]"s"(Sb + 9*(size_t)N), [p3]"s"(Sb + 10*(size_t)N),
          [p4]"s"(Sb + 11*(size_t)N), [p5]"s"(Sb + 12*(size_t)N),
          [p6]"s"(Sb + 13*(size_t)N));
    asm volatile(
        "global_load_dwordx2 %[d0], %[vo], %[p0]\n\t"
        "global_load_dwordx2 %[d1], %[vo], %[p1]\n\t"
        "global_load_dwordx2 %[d2], %[vo], %[p2]\n\t"
        "global_load_dwordx2 %[d3], %[vo], %[p3]\n\t"
        "global_load_dwordx2 %[d4], %[vo], %[p4]\n\t"
        "global_load_dwordx2 %[d5], %[vo], %[p5]\n\t"
        "global_load_dwordx2 %[d6], %[vo], %[p6]\n\t"
        : [d0]"=v"(tv[0]), [d1]"=v"(tv[1]), [d2]"=v"(tv[2]), [d3]"=v"(tv[3]),
          [d4]"=v"(tv[4]), [d5]"=v"(tv[5]), [d6]"=v"(tv[6])
        : [vo]"v"(voff),
          [p0]"s"(Tb + 0*(size_t)N), [p1]"s"(Tb + 1*(size_t)N),
          [p2]"s"(Tb + 2*(size_t)N), [p3]"s"(Tb + 3*(size_t)N),
          [p4]"s"(Tb + 4*(size_t)N), [p5]"s"(Tb + 5*(size_t)N),
          [p6]"s"(Tb + 6*(size_t)N));
    asm volatile(
        "global_load_dwordx2 %[d0], %[vo], %[p0]\n\t"
        "global_load_dwordx2 %[d1], %[vo], %[p1]\n\t"
        "global_load_dwordx2 %[d2], %[vo], %[p2]\n\t"
        "global_load_dwordx2 %[d3], %[vo], %[p3]\n\t"
        "global_load_dwordx2 %[d4], %[vo], %[p4]\n\t"
        "global_load_dwordx2 %[d5], %[vo], %[p5]\n\t"
        "global_load_dwordx2 %[d6], %[vo], %[p6]\n\t"
        : [d0]"=v"(tv[7]), [d1]"=v"(tv[8]), [d2]"=v"(tv[9]), [d3]"=v"(tv[10]),
          [d4]"=v"(tv[11]), [d5]"=v"(tv[12]), [d6]"=v"(tv[13])
        : [vo]"v"(voff),
          [p0]"s"(Tb + 7*(size_t)N), [p1]"s"(Tb + 8*(size_t)N),
          [p2]"s"(Tb + 9*(size_t)N), [p3]"s"(Tb + 10*(size_t)N),
          [p4]"s"(Tb + 11*(size_t)N), [p5]"s"(Tb + 12*(size_t)N),
          [p6]"s"(Tb + 13*(size_t)N));

    int2 g2 = *reinterpret_cast<const int2*>(gt + (size_t)p * 2 + (size_t)b * 0);
    // (global voxel index = b*N + n = 2p, so gt + 2p)

    // Single drain; all 28 float2 values tied through so nothing hoists above.
    asm volatile("s_waitcnt vmcnt(0)"
        : "+v"(sv[0]), "+v"(sv[1]), "+v"(sv[2]), "+v"(sv[3]), "+v"(sv[4]),
          "+v"(sv[5]), "+v"(sv[6]), "+v"(sv[7]), "+v"(sv[8]), "+v"(sv[9]),
          "+v"(sv[10]), "+v"(sv[11]), "+v"(sv[12]), "+v"(sv[13]),
          "+v"(tv[0]), "+v"(tv[1]), "+v"(tv[2]), "+v"(tv[3]), "+v"(tv[4]),
          "+v"(tv[5]), "+v"(tv[6]), "+v"(tv[7]), "+v"(tv[8]), "+v"(tv[9]),
          "+v"(tv[10]), "+v"(tv[11]), "+v"(tv[12]), "+v"(tv[13]));
    __builtin_amdgcn_sched_barrier(0);

    float Zs0 = 0.f, Zt0 = 0.f, At0 = 0.f, As0 = 0.f;
    float Zs1 = 0.f, Zt1 = 0.f, At1 = 0.f, As1 = 0.f;
#pragma unroll
    for (int c = 0; c < NCLS; ++c) {
        float et0 = __expf(tv[c].x), et1 = __expf(tv[c].y);
        Zt0 += et0;                     Zt1 += et1;
        At0 = fmaf(et0, tv[c].x, At0);  At1 = fmaf(et1, tv[c].y, At1);
        As0 = fmaf(et0, sv[c].x, As0);  As1 = fmaf(et1, sv[c].y, As1);
        Zs0 += __expf(sv[c].x);         Zs1 += __expf(sv[c].y);
    }
    float kl0 = (At0 - As0) / Zt0 - __logf(Zt0) + __logf(Zs0);
    float kl1 = (At1 - As1) / Zt1 - __logf(Zt1) + __logf(Zs1);

    int c0 = min(max(g2.x, 0), NCLS - 1);
    int c1 = min(max(g2.y, 0), NCLS - 1);
    atomicAdd(&lsum[b * NCLS + c0], kl0);
    atomicAdd(&lcnt[b * NCLS + c0], 1);
    atomicAdd(&lsum[b * NCLS + c1], kl1);
    atomicAdd(&lcnt[b * NCLS + c1], 1);

    __syncthreads();
    if (threadIdx.x < NUM_BINS) {
        atomicAdd(&gsums[threadIdx.x], lsum[threadIdx.x]);
        atomicAdd(&gcnts[threadIdx.x], lcnt[threadIdx.x]);
    }
}

__global__ void kd_finalize(const float* __restrict__ sums,
                            const int* __restrict__ counts,
                            float* __restrict__ out) {
    if (threadIdx.x == 0) {
        float loss = 0.0f;
        for (int b = 0; b < BATCH; ++b) {
            for (int cls = 1; cls < NCLS; ++cls) {   // class 0 (background) excluded
                int idx = b * NCLS + cls;
                int cnt = counts[idx];
                if (cnt > 0) loss += sums[idx] / ((float)NCLS * (float)cnt);
            }
        }
        out[0] = loss;  // TAU^2 = 1, LOSS_WEIGHT = 1
    }
}

extern "C" void kernel_launch(void* const* d_in, const int* in_sizes, int n_in,
                              void* d_out, int out_size, void* d_ws, size_t ws_size,
                              hipStream_t stream) {
    const float* S = (const float*)d_in[0];
    const float* T = (const float*)d_in[1];
    const int* gt = (const int*)d_in[2];
    float* out = (float*)d_out;

    float* sums = (float*)d_ws;
    int* cnts = (int*)((char*)d_ws + NUM_BINS * sizeof(float));

    const int totalVox = in_sizes[2];       // B * 96^3 = 1,769,472 = 3456 * 512
    const int N = totalVox / BATCH;         // 884,736 (divisible by 512)

    const int block = 256;
    const int grid = totalVox / (block * 2);  // 3456, exact; 2 voxels/thread

    kd_zero_bins<<<1, 64, 0, stream>>>(sums, cnts);
    kd_kl_mlp2<<<grid, block, 0, stream>>>(S, T, gt, sums, cnts, N);
    kd_finalize<<<1, 64, 0, stream>>>(sums, cnts, out);
}

// Round 8
// 45.595 us; speedup vs baseline: 4.7651x; 2.6549x over previous
//
#include <hip/hip_runtime.h>
#include <stdint.h>

#define NCLS 14
#define BATCH 2
#define NUM_BINS (BATCH * NCLS)   // 28
#define KSPREAD 64                // per-bin atomic spread factor

// d_ws layout: float fsum[NUM_BINS*KSPREAD] | int fcnt[NUM_BINS*KSPREAD]
// (1792 floats + 1792 ints = 14.3 KB)

__global__ void kd_zero(float* __restrict__ fsum, int* __restrict__ fcnt) {
    int i = blockIdx.x * blockDim.x + threadIdx.x;   // grid covers 1792 exactly
    fsum[i] = 0.0f;
    fcnt[i] = 0;
}

__global__ __launch_bounds__(256) void kd_kl_part(
        const float* __restrict__ S, const float* __restrict__ T,
        const int* __restrict__ gt,
        float* __restrict__ fsum, int* __restrict__ fcnt,
        int N /* voxels per batch image */) {
    __shared__ float lsum[NUM_BINS];
    __shared__ int lcnt[NUM_BINS];
    if (threadIdx.x < NUM_BINS) { lsum[threadIdx.x] = 0.0f; lcnt[threadIdx.x] = 0; }
    __syncthreads();

    const int gid = blockIdx.x * blockDim.x + threadIdx.x;
    const int v0 = gid * 4;            // 4 voxels/thread; block covers 1024 voxels
    const int b = (v0 >= N) ? 1 : 0;   // N % 1024 == 0: block never straddles
    const int n = v0 - b * N;

    const float4* Sp = reinterpret_cast<const float4*>(S + (size_t)(b * NCLS) * N + n);
    const float4* Tp = reinterpret_cast<const float4*>(T + (size_t)(b * NCLS) * N + n);
    const int quartN = N >> 2;

    float4 sv[NCLS], tv[NCLS];
#pragma unroll
    for (int c = 0; c < NCLS; ++c) sv[c] = Sp[c * quartN];
#pragma unroll
    for (int c = 0; c < NCLS; ++c) tv[c] = Tp[c * quartN];
    int4 g = *reinterpret_cast<const int4*>(gt + v0);

    float Zs[4] = {0,0,0,0}, Zt[4] = {0,0,0,0};
    float At[4] = {0,0,0,0}, As[4] = {0,0,0,0};
#pragma unroll
    for (int c = 0; c < NCLS; ++c) {
        float s[4] = {sv[c].x, sv[c].y, sv[c].z, sv[c].w};
        float t[4] = {tv[c].x, tv[c].y, tv[c].z, tv[c].w};
#pragma unroll
        for (int v = 0; v < 4; ++v) {
            float et = __expf(t[v]);
            Zt[v] += et;
            At[v] = fmaf(et, t[v], At[v]);
            As[v] = fmaf(et, s[v], As[v]);
            Zs[v] += __expf(s[v]);
        }
    }

    int cls[4] = {g.x, g.y, g.z, g.w};
#pragma unroll
    for (int v = 0; v < 4; ++v) {
        // kl = sum_c q(logq - logp) = (At - As)/Zt - log(Zt) + log(Zs)
        float kl = (At[v] - As[v]) / Zt[v] - __logf(Zt[v]) + __logf(Zs[v]);
        int c = min(max(cls[v], 0), NCLS - 1);
        atomicAdd(&lsum[b * NCLS + c], kl);
        atomicAdd(&lcnt[b * NCLS + c], 1);
    }

    __syncthreads();
    // Spread global accumulation 64-way: per-line atomic chain = 1728/64 = 27.
    if (threadIdx.x < NUM_BINS) {
        const int slot = blockIdx.x & (KSPREAD - 1);
        atomicAdd(&fsum[threadIdx.x * KSPREAD + slot], lsum[threadIdx.x]);
        atomicAdd(&fcnt[threadIdx.x * KSPREAD + slot], lcnt[threadIdx.x]);
    }
}

__global__ void kd_final(const float* __restrict__ fsum,
                         const int* __restrict__ fcnt,
                         float* __restrict__ out) {
    __shared__ float terms[64];
    const int t = threadIdx.x;
    float term = 0.0f;
    if (t < NUM_BINS) {
        const float4* fp = reinterpret_cast<const float4*>(fsum + t * KSPREAD);
        const int4* cp = reinterpret_cast<const int4*>(fcnt + t * KSPREAD);
        float s = 0.0f; int n = 0;
#pragma unroll
        for (int i = 0; i < KSPREAD / 4; ++i) {
            float4 v = fp[i]; s += (v.x + v.y) + (v.z + v.w);
            int4 c = cp[i];   n += (c.x + c.y) + (c.z + c.w);
        }
        const int cls = t % NCLS;   // bin = b*NCLS + cls
        if (cls != 0 && n > 0) term = s / ((float)NCLS * (float)n);
    }
    terms[t] = term;
    __syncthreads();
    if (t == 0) {
        float loss = 0.0f;
#pragma unroll
        for (int i = 0; i < 64; ++i) loss += terms[i];
        out[0] = loss;   // TAU^2 = 1, LOSS_WEIGHT = 1
    }
}

extern "C" void kernel_launch(void* const* d_in, const int* in_sizes, int n_in,
                              void* d_out, int out_size, void* d_ws, size_t ws_size,
                              hipStream_t stream) {
    const float* S = (const float*)d_in[0];
    const float* T = (const float*)d_in[1];
    const int* gt = (const int*)d_in[2];
    float* out = (float*)d_out;

    float* fsum = (float*)d_ws;
    int* fcnt = (int*)((char*)d_ws + NUM_BINS * KSPREAD * sizeof(float));

    const int totalVox = in_sizes[2];       // 1,769,472 = 1728 * 1024
    const int N = totalVox / BATCH;         // 884,736 (divisible by 1024)

    const int block = 256;
    const int grid = totalVox / (block * 4);  // 1728 blocks, 4 voxels/thread

    kd_zero<<<(NUM_BINS * KSPREAD) / 256, 256, 0, stream>>>(fsum, fcnt);  // 7 blocks
    kd_kl_part<<<grid, block, 0, stream>>>(S, T, gt, fsum, fcnt, N);
    kd_final<<<1, 64, 0, stream>>>(fsum, fcnt, out);
}